// Round 13
// baseline (21.321 us; speedup 1.0000x reference)
//
#include <hip/hip_runtime.h>
#include <math.h>

// GaussianMixtureLoss: loss = CONST - mean_{b,n}( ln sum_m exp(p·g - |g|²/2) - |p|²/2 )
// B=4, N=4096, M=4096, D=3, SIGMA=1.
// R13: NO mixture LDS staging. gm_prep writes the prescaled Schraudolph
// table (K*g, BIAS - K/2*|g|²) to ws (256 KB, L2/L3-resident); gm_main's
// inner loop reads float4 straight from L2 (per wave j-iter: 32 consecutive
// float4, coalesced; unroll-8 hides ~200cyc L2 latency). Deletes both
// staging phases + barriers that cost ~3-4us in R12. Inner math is
// byte-identical to R12 (Schraudolph folded into table, pure pk_fma chain).
#define BATCH 4
#define NPTS 4096
#define NMIX 4096
#define THREADS 256
#define PPB 16                // points per block
#define PPT 8                 // points per thread (4x v2f)
#define SCH 128               // mixture lane-pairs per block
#define JITER (NMIX / SCH)    // 32 j-iterations per thread
#define NBLOCKS ((BATCH * NPTS) / PPB)  // 1024

#define LN2 0.6931471805599453f
#define CONST_TERM 0.9189385332046727f  // 0.5*log(2*pi)
#define INV_COUNT (1.0f / (float)(BATCH * NPTS))
// Schraudolph folded constants: K = 2^23*log2(e); BIAS = 2^23*(127-0.0563)
#define SEXP_K    12102203.0f
#define SEXP_BIAS 1.06488094e9f

typedef float v2f __attribute__((ext_vector_type(2)));

__device__ __forceinline__ float fast_log2(float x) {
#if __has_builtin(__builtin_amdgcn_logf)
  return __builtin_amdgcn_logf(x);    // raw v_log_f32 (only 16K of these)
#else
  return log2f(x);
#endif
}

// Prep: prescaled mixture table, one float4 per mixture. 256 KB total.
__global__ __launch_bounds__(THREADS) void gm_prep(
    const float* __restrict__ gt, float4* __restrict__ tab) {
  const int i = blockIdx.x * THREADS + threadIdx.x;  // 0..16383
  const float* g = gt + (size_t)i * 3;
  float gx = g[0], gy = g[1], gz = g[2];
  float n2 = fmaf(gx, gx, fmaf(gy, gy, gz * gz));
  tab[i] = make_float4(SEXP_K * gx, SEXP_K * gy, SEXP_K * gz,
                       fmaf(n2, -0.5f * SEXP_K, SEXP_BIAS));
}

__global__ __launch_bounds__(THREADS) void gm_main(
    const float4* __restrict__ tab, const float* __restrict__ pred,
    float* __restrict__ bsum) {
  __shared__ float comb[SCH * (PPB + 1)];  // 8.5 KB tail combine
  __shared__ float wpart[64];

  const int t = threadIdx.x;
  const int b = blockIdx.x >> 8;             // 256 blocks per batch
  const int n0 = (blockIdx.x & 255) * PPB;
  const int c = t >> 1;                      // mixture lane-pair 0..127
  const int pi = (t & 1) * PPT;              // point base 0 or 8

  v2f px[4], py[4], pz[4], acc[4];
#pragma unroll
  for (int k = 0; k < 4; ++k) {
    const float* p = pred + ((size_t)(b * NPTS + n0 + pi + 2 * k)) * 3;
    px[k] = (v2f){p[0], p[3]};
    py[k] = (v2f){p[1], p[4]};
    pz[k] = (v2f){p[2], p[5]};
    acc[k] = (v2f){0.f, 0.f};
  }

  // inner: direct L2 reads, wave reads 32 consecutive float4 per j
  const float4* tb = tab + (size_t)b * NMIX + c;
#pragma unroll 8
  for (int j = 0; j < JITER; ++j) {
    float4 gv = tb[(size_t)SCH * j];
    v2f bx = {gv.x, gv.x}, by = {gv.y, gv.y};
    v2f bz = {gv.z, gv.z}, bw = {gv.w, gv.w};
#pragma unroll
    for (int k = 0; k < 4; ++k) {
      v2f d = __builtin_elementwise_fma(px[k], bx,
              __builtin_elementwise_fma(py[k], by,
              __builtin_elementwise_fma(pz[k], bz, bw)));
      v2f e;
      e.x = __builtin_bit_cast(float, (int)d.x);  // Schraudolph exp
      e.y = __builtin_bit_cast(float, (int)d.y);
      acc[k] += e;
    }
  }

#pragma unroll
  for (int k = 0; k < 4; ++k) {
    comb[c * (PPB + 1) + pi + 2 * k]     = acc[k].x;
    comb[c * (PPB + 1) + pi + 2 * k + 1] = acc[k].y;
  }
  __syncthreads();

  {
    const int p = t & 15, g = t >> 4;
    float s = 0.f;
#pragma unroll
    for (int j = 0; j < 8; ++j) s += comb[(g * 8 + j) * (PPB + 1) + p];
    s += __shfl_down(s, 32, 64);
    s += __shfl_down(s, 16, 64);
    if ((t & 63) < 16) wpart[(t >> 6) * 16 + (t & 15)] = s;
  }
  __syncthreads();

  if (t < 16) {
    float s = wpart[t] + wpart[16 + t] + wpart[32 + t] + wpart[48 + t];
    const float* p = pred + ((size_t)(b * NPTS + n0 + t)) * 3;
    float hp2 = 0.5f * (p[0] * p[0] + p[1] * p[1] + p[2] * p[2]);
    float ll = (LN2 * fast_log2(s) - hp2) * INV_COUNT;
#pragma unroll
    for (int off = 8; off > 0; off >>= 1) ll += __shfl_down(ll, off, 16);
    if (t == 0) bsum[blockIdx.x] = ll;
  }
}

__global__ __launch_bounds__(THREADS) void gm_reduce(
    const float* __restrict__ bsum, float* __restrict__ out) {
  const int t = threadIdx.x;
  float v = (bsum[t] + bsum[t + 256]) + (bsum[t + 512] + bsum[t + 768]);
  for (int off = 32; off > 0; off >>= 1) v += __shfl_down(v, off, 64);
  __shared__ float w[4];
  if ((t & 63) == 0) w[t >> 6] = v;
  __syncthreads();
  if (t == 0) out[0] = CONST_TERM - ((w[0] + w[1]) + (w[2] + w[3]));
}

extern "C" void kernel_launch(void* const* d_in, const int* in_sizes, int n_in,
                              void* d_out, int out_size, void* d_ws, size_t ws_size,
                              hipStream_t stream) {
  const float* pred = (const float*)d_in[0];
  const float* gt   = (const float*)d_in[1];
  float* out = (float*)d_out;

  float4* tab = (float4*)d_ws;                         // 16384 float4 = 256 KB
  float* bsum = (float*)d_ws + 4 * BATCH * NMIX;       // +1024 floats

  gm_prep<<<(BATCH * NMIX) / THREADS, THREADS, 0, stream>>>(gt, tab);
  gm_main<<<NBLOCKS, THREADS, 0, stream>>>(tab, pred, bsum);
  gm_reduce<<<1, THREADS, 0, stream>>>(bsum, out);
}

// Round 14
// 17.174 us; speedup vs baseline: 1.2415x; 1.2415x over previous
//
#include <hip/hip_runtime.h>
#include <math.h>

// GaussianMixtureLoss: loss = CONST - mean_{b,n}( ln sum_m exp(p·g - |g|²/2) - |p|²/2 )
// B=4, N=4096, M=4096, D=3, SIGMA=1.
// R14: mixture-vectorized inner loop (vs R12's point-vectorized).
//  - Thread = 4 SCALAR points x 2 mixtures per j-iter. The pk-fma broadcast
//    operands are now the LOOP-INVARIANT point coords (hoisted pairs) —
//    kills the 8 per-j splat movs R12 paid for.
//  - 3-fma dot chain forced to v_pk_fma_f32 via inline asm (rules out
//    compiler scalarization, the suspected remaining 2x inst bloat).
//  - LDS layout: mixture pair s -> gsh[2s]={Kgx0,Kgx1,Kgy0,Kgy1},
//    gsh[2s+1]={Kgz0,Kgz1,w0,w1}, w = BIAS - K/2*|g|² (Schraudolph folded).
//  - staging/tail/2-dispatch structure = R12 (17.16us base).
#define BATCH 4
#define NPTS 4096
#define NMIX 4096
#define THREADS 256
#define PPB 16                // points per block
#define MSTAGE 2048           // mixtures staged per pass (1024 pairs, 32 KB)
#define PASSES (NMIX / MSTAGE)
#define JITER 16              // 64 pairs (128 mixtures) per block per j
#define NBLOCKS ((BATCH * NPTS) / PPB)  // 1024

#define LN2 0.6931471805599453f
#define CONST_TERM 0.9189385332046727f  // 0.5*log(2*pi)
#define INV_COUNT (1.0f / (float)(BATCH * NPTS))
// Schraudolph folded: K = 2^23*log2(e); BIAS = 2^23*(127-0.0563)
#define SEXP_K    12102203.0f
#define SEXP_BIAS 1.06488094e9f

typedef float v2f __attribute__((ext_vector_type(2)));

__device__ __forceinline__ float fast_log2(float x) {
#if __has_builtin(__builtin_amdgcn_logf)
  return __builtin_amdgcn_logf(x);
#else
  return log2f(x);
#endif
}

// guaranteed packed fp32 fma: d = a*b + c on both halves of a VGPR pair
__device__ __forceinline__ v2f pk_fma(v2f a, v2f b, v2f c) {
  v2f d;
  asm("v_pk_fma_f32 %0, %1, %2, %3" : "=v"(d) : "v"(a), "v"(b), "v"(c));
  return d;
}

__global__ __launch_bounds__(THREADS) void gm_main(
    const float* __restrict__ pred, const float* __restrict__ gt,
    float* __restrict__ bsum) {
  __shared__ float4 gsh[MSTAGE];   // 32 KB (1024 pairs x 2 float4)
  __shared__ float wpart[64];      // [4 waves][16 cols]
  float* comb = (float*)gsh;       // aliased tail buffer [64][17]

  const int t = threadIdx.x;
  const int b = blockIdx.x >> 8;             // 256 blocks per batch
  const int n0 = (blockIdx.x & 255) * PPB;
  const int pl = t & 3;                      // point sub-group 0..3
  const int ml = t >> 2;                     // mixture-pair lane 0..63

  // 4 scalar points, hoisted as broadcast pairs for pk_fma
  v2f px2[4], py2[4], pz2[4], acc[4];
#pragma unroll
  for (int k = 0; k < 4; ++k) {
    const float* p = pred + ((size_t)(b * NPTS + n0 + pl * 4 + k)) * 3;
    px2[k] = (v2f){p[0], p[0]};
    py2[k] = (v2f){p[1], p[1]};
    pz2[k] = (v2f){p[2], p[2]};
    acc[k] = (v2f){0.f, 0.f};
  }

  for (int q = 0; q < PASSES; ++q) {
    __syncthreads();  // prior-pass readers done
#pragma unroll
    for (int i = 0; i < 4; ++i) {
      int s = t + i * THREADS;  // pair index 0..1023
      const float2* g = (const float2*)(gt +
          ((size_t)(b * NMIX + q * MSTAGE + 2 * s)) * 3);
      float2 g01 = g[0], g23 = g[1], g45 = g[2];
      // mixture 2s: (g01.x, g01.y, g23.x); 2s+1: (g23.y, g45.x, g45.y)
      float n20 = fmaf(g01.x, g01.x, fmaf(g01.y, g01.y, g23.x * g23.x));
      float n21 = fmaf(g23.y, g23.y, fmaf(g45.x, g45.x, g45.y * g45.y));
      gsh[2 * s]     = make_float4(SEXP_K * g01.x, SEXP_K * g23.y,
                                   SEXP_K * g01.y, SEXP_K * g45.x);
      gsh[2 * s + 1] = make_float4(SEXP_K * g23.x, SEXP_K * g45.y,
                                   fmaf(n20, -0.5f * SEXP_K, SEXP_BIAS),
                                   fmaf(n21, -0.5f * SEXP_K, SEXP_BIAS));
    }
    __syncthreads();

#pragma unroll 4
    for (int j = 0; j < JITER; ++j) {
      int s = ml + 64 * j;
      float4 a = gsh[2 * s];      // {Kgx0,Kgx1,Kgy0,Kgy1}
      float4 c4 = gsh[2 * s + 1]; // {Kgz0,Kgz1,w0,w1}
      v2f gx2 = (v2f){a.x, a.y}, gy2 = (v2f){a.z, a.w};
      v2f gz2 = (v2f){c4.x, c4.y}, w2 = (v2f){c4.z, c4.w};
#pragma unroll
      for (int k = 0; k < 4; ++k) {
        v2f d = pk_fma(pz2[k], gz2, w2);
        d = pk_fma(py2[k], gy2, d);
        d = pk_fma(px2[k], gx2, d);
        // Schraudolph: exp ~= bitcast((int)d)
        acc[k].x += __builtin_bit_cast(float, (int)d.x);
        acc[k].y += __builtin_bit_cast(float, (int)d.y);
      }
    }
  }

  __syncthreads();  // all gsh reads done before aliasing as comb

  // comb[ml][pl*4+k]: each thread's partial (both mixture halves summed)
#pragma unroll
  for (int k = 0; k < 4; ++k)
    comb[ml * (PPB + 1) + pl * 4 + k] = acc[k].x + acc[k].y;
  __syncthreads();

  {
    const int col = t & 15, grp = t >> 4;  // grp 0..15: 4 rows each
    float s = 0.f;
#pragma unroll
    for (int r = 0; r < 4; ++r) s += comb[(grp * 4 + r) * (PPB + 1) + col];
    s += __shfl_down(s, 32, 64);
    s += __shfl_down(s, 16, 64);
    if ((t & 63) < 16) wpart[(t >> 6) * 16 + col] = s;
  }
  __syncthreads();

  if (t < 16) {
    float s = wpart[t] + wpart[16 + t] + wpart[32 + t] + wpart[48 + t];
    const float* p = pred + ((size_t)(b * NPTS + n0 + t)) * 3;
    float hp2 = 0.5f * (p[0] * p[0] + p[1] * p[1] + p[2] * p[2]);
    float ll = (LN2 * fast_log2(s) - hp2) * INV_COUNT;
#pragma unroll
    for (int off = 8; off > 0; off >>= 1) ll += __shfl_down(ll, off, 16);
    if (t == 0) bsum[blockIdx.x] = ll;
  }
}

__global__ __launch_bounds__(THREADS) void gm_reduce(
    const float* __restrict__ bsum, float* __restrict__ out) {
  const int t = threadIdx.x;
  float v = (bsum[t] + bsum[t + 256]) + (bsum[t + 512] + bsum[t + 768]);
  for (int off = 32; off > 0; off >>= 1) v += __shfl_down(v, off, 64);
  __shared__ float w[4];
  if ((t & 63) == 0) w[t >> 6] = v;
  __syncthreads();
  if (t == 0) out[0] = CONST_TERM - ((w[0] + w[1]) + (w[2] + w[3]));
}

extern "C" void kernel_launch(void* const* d_in, const int* in_sizes, int n_in,
                              void* d_out, int out_size, void* d_ws, size_t ws_size,
                              hipStream_t stream) {
  const float* pred = (const float*)d_in[0];
  const float* gt   = (const float*)d_in[1];
  float* out = (float*)d_out;
  float* bsum = (float*)d_ws;  // 1024 floats, fully overwritten every call

  gm_main<<<NBLOCKS, THREADS, 0, stream>>>(pred, gt, bsum);
  gm_reduce<<<1, THREADS, 0, stream>>>(bsum, out);
}